// Round 1
// baseline (1158.500 us; speedup 1.0000x reference)
//
#include <hip/hip_runtime.h>

#define B_   32
#define NQ_  4096
#define NK_  77
#define H_   8
#define DH_  40
#define IN_  320
#define CD_  768
#define M_   (B_ * NQ_)   // 131072 rows

typedef __attribute__((ext_vector_type(8))) short bf16x8;
typedef __attribute__((ext_vector_type(4))) float f32x4;

__device__ __forceinline__ unsigned short f2bf(float f) {
  union { float f; unsigned int i; } v; v.f = f;
  unsigned int i = v.i;
  i += 0x7fffu + ((i >> 16) & 1u);   // round-to-nearest-even
  return (unsigned short)(i >> 16);
}
__device__ __forceinline__ unsigned int pack2(float a, float b) {
  return (unsigned int)f2bf(a) | ((unsigned int)f2bf(b) << 16);
}
__device__ __forceinline__ void bf2x(unsigned int w, float& lo, float& hi) {
  union { unsigned int i; float f; } a, b;
  a.i = w << 16; b.i = w & 0xffff0000u;
  lo = a.f; hi = b.f;
}

// ---------------------------------------------------------------------------
// K/V projection: K = (ctx @ Wk^T) * gamma_k, V likewise.
// ctx: [2464, 768] fp32.  Out: Kh/Vh [B, H, 77, 40] fp32.
// One block = 8 context rows staged in LDS; thread c owns output column c.
// ---------------------------------------------------------------------------
__global__ __launch_bounds__(320) void kv_proj(
    const float* __restrict__ ctx, const float* __restrict__ Wk,
    const float* __restrict__ Wv, const float* __restrict__ gk,
    const float* __restrict__ gv, float* __restrict__ Kh,
    float* __restrict__ Vh)
{
  __shared__ alignas(16) float lds[8 * CD_];
  const int r0 = blockIdx.x * 8;
  {
    const float4* src = (const float4*)(ctx + (size_t)r0 * CD_);
    float4* dst = (float4*)lds;
    for (int i = threadIdx.x; i < 8 * CD_ / 4; i += 320) dst[i] = src[i];
  }
  __syncthreads();
  const int c = threadIdx.x;   // 0..319
  float aK[8] = {0,0,0,0,0,0,0,0};
  float aV[8] = {0,0,0,0,0,0,0,0};
  const float* wkp = Wk + (size_t)c * CD_;
  const float* wvp = Wv + (size_t)c * CD_;
  for (int j = 0; j < CD_; j += 4) {
    const float4 wk = *(const float4*)(wkp + j);
    const float4 wv = *(const float4*)(wvp + j);
#pragma unroll
    for (int r = 0; r < 8; ++r) {
      const float4 xr = *(const float4*)(&lds[r * CD_ + j]);   // LDS broadcast
      aK[r] += wk.x * xr.x + wk.y * xr.y + wk.z * xr.z + wk.w * xr.w;
      aV[r] += wv.x * xr.x + wv.y * xr.y + wv.z * xr.z + wv.w * xr.w;
    }
  }
  const float gkc = gk[c], gvc = gv[c];
  const int h = c / DH_, d = c % DH_;
#pragma unroll
  for (int r = 0; r < 8; ++r) {
    const int fr = r0 + r;
    const int bb = fr / NK_, pos = fr % NK_;
    const int idx = ((bb * H_ + h) * NK_ + pos) * DH_ + d;
    Kh[idx] = aK[r] * gkc;
    Vh[idx] = aV[r] * gvc;
  }
}

// ---------------------------------------------------------------------------
// GEMM: C[M,320] = A[M,320] @ W[320,320]^T with per-column epilogue.
// MODE 0: A = x fp32 (converted to bf16 while staging), C = Q bf16, *gamma.
// MODE 1: A = O bf16 (from ws), C = d_out fp32, (+bias)*gamma.
// Block: 256 thr (4 waves), tile 64x64, BK=32, mfma_f32_16x16x32_bf16.
// A/B frag layout: [row = lane&15][k = (lane>>4)*8 + j] -> contiguous 16B.
// C/D layout: col = lane&15, row = (lane>>4)*4 + reg   (m89/m91-verified).
// ---------------------------------------------------------------------------
template <int MODE>
__global__ __launch_bounds__(256) void gemm_proj(
    const void* __restrict__ Ap, const float* __restrict__ W,
    const float* __restrict__ gamma, const float* __restrict__ bias,
    void* __restrict__ Cp)
{
  constexpr int LDA = 40;   // bf16 elems per LDS row (32 + 8 pad)
  __shared__ alignas(16) unsigned short As[64 * LDA];
  __shared__ alignas(16) unsigned short Bs[64 * LDA];
  const int m0 = blockIdx.x * 64;
  const int n0 = blockIdx.y * 64;
  const int tid = threadIdx.x;
  const int wave = tid >> 6;
  const int lane = tid & 63;
  const int lm = lane & 15;
  const int quad = lane >> 4;

  f32x4 acc0 = {0.f, 0.f, 0.f, 0.f};
  f32x4 acc1 = acc0, acc2 = acc0, acc3 = acc0;

  for (int k0 = 0; k0 < IN_; k0 += 32) {
    if (MODE == 0) {
      const float* A = (const float*)Ap;
#pragma unroll
      for (int c = tid; c < 512; c += 256) {
        const int row = c >> 3, kq = (c & 7) << 2;
        const float4 v = *(const float4*)(A + (size_t)(m0 + row) * IN_ + k0 + kq);
        uint2 p; p.x = pack2(v.x, v.y); p.y = pack2(v.z, v.w);
        *(uint2*)(&As[row * LDA + kq]) = p;
      }
    } else {
      const unsigned short* A = (const unsigned short*)Ap;
      const int row = tid >> 2, kq = (tid & 3) << 3;
      *(uint4*)(&As[row * LDA + kq]) =
          *(const uint4*)(A + (size_t)(m0 + row) * IN_ + k0 + kq);
    }
#pragma unroll
    for (int c = tid; c < 512; c += 256) {
      const int row = c >> 3, kq = (c & 7) << 2;
      const float4 v = *(const float4*)(W + (size_t)(n0 + row) * IN_ + k0 + kq);
      uint2 p; p.x = pack2(v.x, v.y); p.y = pack2(v.z, v.w);
      *(uint2*)(&Bs[row * LDA + kq]) = p;
    }
    __syncthreads();
    const bf16x8 a  = *(const bf16x8*)(&As[(wave * 16 + lm) * LDA + quad * 8]);
    const bf16x8 b0 = *(const bf16x8*)(&Bs[( 0 + lm) * LDA + quad * 8]);
    const bf16x8 b1 = *(const bf16x8*)(&Bs[(16 + lm) * LDA + quad * 8]);
    const bf16x8 b2 = *(const bf16x8*)(&Bs[(32 + lm) * LDA + quad * 8]);
    const bf16x8 b3 = *(const bf16x8*)(&Bs[(48 + lm) * LDA + quad * 8]);
    acc0 = __builtin_amdgcn_mfma_f32_16x16x32_bf16(a, b0, acc0, 0, 0, 0);
    acc1 = __builtin_amdgcn_mfma_f32_16x16x32_bf16(a, b1, acc1, 0, 0, 0);
    acc2 = __builtin_amdgcn_mfma_f32_16x16x32_bf16(a, b2, acc2, 0, 0, 0);
    acc3 = __builtin_amdgcn_mfma_f32_16x16x32_bf16(a, b3, acc3, 0, 0, 0);
    __syncthreads();
  }

  const f32x4 accs[4] = {acc0, acc1, acc2, acc3};
#pragma unroll
  for (int t = 0; t < 4; ++t) {
#pragma unroll
    for (int r = 0; r < 4; ++r) {
      const int row = m0 + wave * 16 + quad * 4 + r;
      const int col = n0 + t * 16 + lm;
      const float v = accs[t][r];
      if (MODE == 0) {
        ((unsigned short*)Cp)[(size_t)row * IN_ + col] = f2bf(v * gamma[col]);
      } else {
        ((float*)Cp)[(size_t)row * IN_ + col] = (v + bias[col]) * gamma[col];
      }
    }
  }
}

// ---------------------------------------------------------------------------
// Fused attention: per (b, h, 256-row q-tile). K/V (77x40 fp32) in LDS.
// One thread = one q row. 2-pass (max, then exp+accumulate), fp32 math.
// Reads Q bf16 slice from ws and overwrites it with O bf16 (disjoint per block).
// ---------------------------------------------------------------------------
__global__ __launch_bounds__(256) void attn_fused(
    const float* __restrict__ Kh, const float* __restrict__ Vh,
    unsigned short* __restrict__ QO)
{
  __shared__ alignas(16) float Ks[NK_ * DH_];
  __shared__ alignas(16) float Vs[NK_ * DH_];
  const int b = blockIdx.z, h = blockIdx.y, qt = blockIdx.x;
  const size_t bh = (size_t)(b * H_ + h) * (NK_ * DH_);
  {
    const float4* Kp = (const float4*)(Kh + bh);
    const float4* Vp = (const float4*)(Vh + bh);
    for (int i = threadIdx.x; i < NK_ * DH_ / 4; i += 256) {
      ((float4*)Ks)[i] = Kp[i];
      ((float4*)Vs)[i] = Vp[i];
    }
  }
  __syncthreads();
  const int row = b * NQ_ + qt * 256 + threadIdx.x;
  unsigned short* qptr = QO + (size_t)row * IN_ + h * DH_;

  float q[DH_];
  {
    const uint4* qp4 = (const uint4*)qptr;
#pragma unroll
    for (int i = 0; i < 5; ++i) {
      const uint4 u = qp4[i];
      bf2x(u.x, q[i * 8 + 0], q[i * 8 + 1]);
      bf2x(u.y, q[i * 8 + 2], q[i * 8 + 3]);
      bf2x(u.z, q[i * 8 + 4], q[i * 8 + 5]);
      bf2x(u.w, q[i * 8 + 6], q[i * 8 + 7]);
    }
  }
  const float scale = 0.15811388300841897f;   // 1/sqrt(40)

  float mx = -1e30f;
  for (int k = 0; k < NK_; ++k) {
    float s = 0.f;
#pragma unroll
    for (int d = 0; d < DH_; d += 4) {
      const float4 kv = *(const float4*)(&Ks[k * DH_ + d]);   // broadcast
      s += q[d] * kv.x + q[d + 1] * kv.y + q[d + 2] * kv.z + q[d + 3] * kv.w;
    }
    mx = fmaxf(mx, s);
  }
  mx *= scale;

  float l = 0.f;
  float o[DH_];
#pragma unroll
  for (int d = 0; d < DH_; ++d) o[d] = 0.f;

  for (int k = 0; k < NK_; ++k) {
    float s = 0.f;
#pragma unroll
    for (int d = 0; d < DH_; d += 4) {
      const float4 kv = *(const float4*)(&Ks[k * DH_ + d]);
      s += q[d] * kv.x + q[d + 1] * kv.y + q[d + 2] * kv.z + q[d + 3] * kv.w;
    }
    const float w = __expf(s * scale - mx);
    l += w;
#pragma unroll
    for (int d = 0; d < DH_; d += 4) {
      const float4 vv = *(const float4*)(&Vs[k * DH_ + d]);
      o[d]     += w * vv.x;
      o[d + 1] += w * vv.y;
      o[d + 2] += w * vv.z;
      o[d + 3] += w * vv.w;
    }
  }
  const float rl = 1.f / l;

  uint4* op4 = (uint4*)qptr;
#pragma unroll
  for (int i = 0; i < 5; ++i) {
    uint4 u;
    u.x = pack2(o[i * 8 + 0] * rl, o[i * 8 + 1] * rl);
    u.y = pack2(o[i * 8 + 2] * rl, o[i * 8 + 3] * rl);
    u.z = pack2(o[i * 8 + 4] * rl, o[i * 8 + 5] * rl);
    u.w = pack2(o[i * 8 + 6] * rl, o[i * 8 + 7] * rl);
    op4[i] = u;
  }
}

// ---------------------------------------------------------------------------
extern "C" void kernel_launch(void* const* d_in, const int* in_sizes, int n_in,
                              void* d_out, int out_size, void* d_ws,
                              size_t ws_size, hipStream_t stream)
{
  const float* x   = (const float*)d_in[0];
  const float* ctx = (const float*)d_in[1];
  const float* Wq  = (const float*)d_in[2];
  const float* Wk  = (const float*)d_in[3];
  const float* Wv  = (const float*)d_in[4];
  const float* Wo  = (const float*)d_in[5];
  const float* bo  = (const float*)d_in[6];
  const float* gq  = (const float*)d_in[7];
  const float* gk  = (const float*)d_in[8];
  const float* gv  = (const float*)d_in[9];
  const float* go  = (const float*)d_in[10];
  float* out = (float*)d_out;

  // Workspace carve-up (needs 90,193,920 B):
  //   q_ws : [131072, 320] bf16  (Q, overwritten in-place with O by attn)
  //   Kh,Vh: [32, 8, 77, 40] fp32 each
  char* ws = (char*)d_ws;
  unsigned short* q_ws = (unsigned short*)ws;
  float* Kh = (float*)(ws + (size_t)M_ * IN_ * 2);
  float* Vh = Kh + (size_t)B_ * H_ * NK_ * DH_;

  kv_proj<<<dim3(2464 / 8), dim3(320), 0, stream>>>(ctx, Wk, Wv, gk, gv, Kh, Vh);
  gemm_proj<0><<<dim3(M_ / 64, IN_ / 64), dim3(256), 0, stream>>>(
      x, Wq, gq, nullptr, q_ws);
  attn_fused<<<dim3(NQ_ / 256, H_, B_), dim3(256), 0, stream>>>(Kh, Vh, q_ws);
  gemm_proj<1><<<dim3(M_ / 64, IN_ / 64), dim3(256), 0, stream>>>(
      q_ws, Wo, go, bo, out);
}

// Round 2
// 748.922 us; speedup vs baseline: 1.5469x; 1.5469x over previous
//
#include <hip/hip_runtime.h>

#define B_   32
#define NQ_  4096
#define NK_  77
#define H_   8
#define DH_  40
#define IN_  320
#define CD_  768
#define M_   (B_ * NQ_)   // 131072 rows

#define NKP_  80    // keys padded for score n-tiles
#define NKP2_ 96    // keys padded for PV k-steps
#define DHP_  48    // dims padded for PV n-tiles
#define KQ_   64    // qk k-dim padded (40 -> 64)

typedef __attribute__((ext_vector_type(8))) short bf16x8;
typedef __attribute__((ext_vector_type(4))) float f32x4;
typedef unsigned short ushort_t;

__device__ __forceinline__ unsigned short f2bf(float f) {
  union { float f; unsigned int i; } v; v.f = f;
  unsigned int i = v.i;
  i += 0x7fffu + ((i >> 16) & 1u);   // round-to-nearest-even
  return (unsigned short)(i >> 16);
}
__device__ __forceinline__ unsigned int pack2(float a, float b) {
  return (unsigned int)f2bf(a) | ((unsigned int)f2bf(b) << 16);
}

// ---------------------------------------------------------------------------
// Convert Wq and Wo (320x320 fp32) to bf16 once. blockIdx.y: 0=Wq, 1=Wo.
// ---------------------------------------------------------------------------
__global__ __launch_bounds__(256) void wcvt(
    const float* __restrict__ Wq, const float* __restrict__ Wo,
    unsigned short* __restrict__ Wqb, unsigned short* __restrict__ Wob)
{
  const int i = blockIdx.x * 256 + threadIdx.x;   // float4 index, < 25600
  const float* src = blockIdx.y ? Wo : Wq;
  unsigned short* dst = blockIdx.y ? Wob : Wqb;
  const float4 v = ((const float4*)src)[i];
  uint2 p; p.x = pack2(v.x, v.y); p.y = pack2(v.z, v.w);
  ((uint2*)dst)[i] = p;
}

// ---------------------------------------------------------------------------
// K/V projection -> bf16, attention-ready layouts.
//   Khb: [B, H, 80, 64] bf16   (K rows; rows>=77 and cols>=40 stay zero)
//   Vtb: [B, H, 48, 96] bf16   (V transposed; rows>=40 and cols>=77 stay zero)
// Buffers pre-zeroed with hipMemsetAsync.
// ---------------------------------------------------------------------------
__global__ __launch_bounds__(320) void kv_proj(
    const float* __restrict__ ctx, const float* __restrict__ Wk,
    const float* __restrict__ Wv, const float* __restrict__ gk,
    const float* __restrict__ gv, unsigned short* __restrict__ Khb,
    unsigned short* __restrict__ Vtb)
{
  __shared__ alignas(16) float lds[8 * CD_];
  const int r0 = blockIdx.x * 8;
  {
    const float4* src = (const float4*)(ctx + (size_t)r0 * CD_);
    float4* dst = (float4*)lds;
    for (int i = threadIdx.x; i < 8 * CD_ / 4; i += 320) dst[i] = src[i];
  }
  __syncthreads();
  const int c = threadIdx.x;   // 0..319
  float aK[8] = {0,0,0,0,0,0,0,0};
  float aV[8] = {0,0,0,0,0,0,0,0};
  const float* wkp = Wk + (size_t)c * CD_;
  const float* wvp = Wv + (size_t)c * CD_;
  for (int j = 0; j < CD_; j += 4) {
    const float4 wk = *(const float4*)(wkp + j);
    const float4 wv = *(const float4*)(wvp + j);
#pragma unroll
    for (int r = 0; r < 8; ++r) {
      const float4 xr = *(const float4*)(&lds[r * CD_ + j]);   // LDS broadcast
      aK[r] += wk.x * xr.x + wk.y * xr.y + wk.z * xr.z + wk.w * xr.w;
      aV[r] += wv.x * xr.x + wv.y * xr.y + wv.z * xr.z + wv.w * xr.w;
    }
  }
  const float gkc = gk[c], gvc = gv[c];
  const int h = c / DH_, d = c % DH_;
#pragma unroll
  for (int r = 0; r < 8; ++r) {
    const int fr = r0 + r;
    const int bb = fr / NK_, pos = fr % NK_;
    const int bh = bb * H_ + h;
    Khb[((size_t)bh * NKP_ + pos) * KQ_ + d]   = f2bf(aK[r] * gkc);
    Vtb[((size_t)bh * DHP_ + d) * NKP2_ + pos] = f2bf(aV[r] * gvc);
  }
}

// ---------------------------------------------------------------------------
// GEMM: C[M,320] = A[M,320] @ W[320,320]^T with per-column epilogue.
// MODE 0: A = x fp32 (converted to bf16 while staging), C = Q bf16, *gamma.
// MODE 1: A = O bf16 (ws), C = d_out fp32, (+bias)*gamma.
// W is pre-converted bf16. Tile 64x64, BK=32, mfma_f32_16x16x32_bf16.
// ---------------------------------------------------------------------------
template <int MODE>
__global__ __launch_bounds__(256) void gemm_proj(
    const void* __restrict__ Ap, const unsigned short* __restrict__ Wb,
    const float* __restrict__ gamma, const float* __restrict__ bias,
    void* __restrict__ Cp)
{
  constexpr int LDA = 40;   // bf16 elems per LDS row (32 + 8 pad)
  __shared__ alignas(16) unsigned short As[64 * LDA];
  __shared__ alignas(16) unsigned short Bs[64 * LDA];
  const int m0 = blockIdx.x * 64;
  const int n0 = blockIdx.y * 64;
  const int tid = threadIdx.x;
  const int wave = tid >> 6;
  const int lane = tid & 63;
  const int lm = lane & 15;
  const int quad = lane >> 4;

  f32x4 acc0 = {0.f, 0.f, 0.f, 0.f};
  f32x4 acc1 = acc0, acc2 = acc0, acc3 = acc0;

  for (int k0 = 0; k0 < IN_; k0 += 32) {
    if (MODE == 0) {
      const float* A = (const float*)Ap;
#pragma unroll
      for (int c = tid; c < 512; c += 256) {
        const int row = c >> 3, kq = (c & 7) << 2;
        const float4 v = *(const float4*)(A + (size_t)(m0 + row) * IN_ + k0 + kq);
        uint2 p; p.x = pack2(v.x, v.y); p.y = pack2(v.z, v.w);
        *(uint2*)(&As[row * LDA + kq]) = p;
      }
    } else {
      const unsigned short* A = (const unsigned short*)Ap;
      const int row = tid >> 2, kq = (tid & 3) << 3;
      *(uint4*)(&As[row * LDA + kq]) =
          *(const uint4*)(A + (size_t)(m0 + row) * IN_ + k0 + kq);
    }
    {
      const int row = tid >> 2, kq = (tid & 3) << 3;
      *(uint4*)(&Bs[row * LDA + kq]) =
          *(const uint4*)(Wb + (size_t)(n0 + row) * IN_ + k0 + kq);
    }
    __syncthreads();
    const bf16x8 a  = *(const bf16x8*)(&As[(wave * 16 + lm) * LDA + quad * 8]);
    const bf16x8 b0 = *(const bf16x8*)(&Bs[( 0 + lm) * LDA + quad * 8]);
    const bf16x8 b1 = *(const bf16x8*)(&Bs[(16 + lm) * LDA + quad * 8]);
    const bf16x8 b2 = *(const bf16x8*)(&Bs[(32 + lm) * LDA + quad * 8]);
    const bf16x8 b3 = *(const bf16x8*)(&Bs[(48 + lm) * LDA + quad * 8]);
    acc0 = __builtin_amdgcn_mfma_f32_16x16x32_bf16(a, b0, acc0, 0, 0, 0);
    acc1 = __builtin_amdgcn_mfma_f32_16x16x32_bf16(a, b1, acc1, 0, 0, 0);
    acc2 = __builtin_amdgcn_mfma_f32_16x16x32_bf16(a, b2, acc2, 0, 0, 0);
    acc3 = __builtin_amdgcn_mfma_f32_16x16x32_bf16(a, b3, acc3, 0, 0, 0);
    __syncthreads();
  }

  const f32x4 accs[4] = {acc0, acc1, acc2, acc3};
#pragma unroll
  for (int t = 0; t < 4; ++t) {
#pragma unroll
    for (int r = 0; r < 4; ++r) {
      const int row = m0 + wave * 16 + quad * 4 + r;
      const int col = n0 + t * 16 + lm;
      const float v = accs[t][r];
      if (MODE == 0) {
        ((unsigned short*)Cp)[(size_t)row * IN_ + col] = f2bf(v * gamma[col]);
      } else {
        ((float*)Cp)[(size_t)row * IN_ + col] = (v + bias[col]) * gamma[col];
      }
    }
  }
}

// ---------------------------------------------------------------------------
// MFMA attention. Block = 256 thr (4 waves) handles (b, h, 128 q rows);
// each wave owns 32 rows (2 m-frags). S = Q.K^T (k 40->64), softmax in regs
// (shfl_xor over the 16 col-lanes), P -> LDS (C-layout -> A-layout), P.V with
// keys padded to 96 against V^T. O overwrites Q slice in ws (bf16).
// LDS: Qs[128x72] + Ks[80x72] overlaid later by Ps[4][32x104]; Vt[48x104].
// ---------------------------------------------------------------------------
#define QT_ 128
__global__ __launch_bounds__(256) void attn_mfma(
    const unsigned short* __restrict__ Khb,
    const unsigned short* __restrict__ Vtb,
    unsigned short* __restrict__ QO)
{
  __shared__ alignas(16) unsigned short smem[14976 + 48 * 104];
  unsigned short* Qs = smem;            // 128 x 72
  unsigned short* Ks = smem + 128 * 72; // 80 x 72
  unsigned short* Vt = smem + 14976;    // 48 x 104
  unsigned short* Ps = smem;            // overlays Qs/Ks: wave w at w*32*104

  const int b = blockIdx.z, h = blockIdx.y, qt = blockIdx.x;
  const int tid = threadIdx.x;
  const int row0 = qt * QT_;
  const size_t qbase = ((size_t)b * NQ_ + row0) * IN_ + h * DH_;

  // ---- stage Q (bf16, zero-pad cols 40..71) ----
  for (int i = tid; i < QT_ * 9; i += 256) {
    const int row = i / 9, seg = i % 9;
    uint4 v = {0u, 0u, 0u, 0u};
    if (seg < 5)
      v = *(const uint4*)(QO + qbase + (size_t)row * IN_ + seg * 8);
    *(uint4*)(&Qs[row * 72 + seg * 8]) = v;
  }
  // ---- stage K [80x64] -> [80x72] (zero-pad cols 64..71) ----
  {
    const unsigned short* src = Khb + (size_t)(b * H_ + h) * NKP_ * KQ_;
    for (int i = tid; i < NKP_ * 9; i += 256) {
      const int row = i / 9, seg = i % 9;
      uint4 v = {0u, 0u, 0u, 0u};
      if (seg < 8) v = *(const uint4*)(src + row * KQ_ + seg * 8);
      *(uint4*)(&Ks[row * 72 + seg * 8]) = v;
    }
  }
  // ---- stage V^T [48x96] -> [48x104] (cols 96..103 never read) ----
  {
    const unsigned short* src = Vtb + (size_t)(b * H_ + h) * DHP_ * NKP2_;
    for (int i = tid; i < DHP_ * 12; i += 256) {
      const int row = i / 12, seg = i % 12;
      *(uint4*)(&Vt[row * 104 + seg * 8]) =
          *(const uint4*)(src + row * NKP2_ + seg * 8);
    }
  }
  __syncthreads();

  const int wave = tid >> 6;
  const int lane = tid & 63;
  const int lm = lane & 15;
  const int quad = lane >> 4;
  const int wrow = wave * 32;   // wave's 32-row window within the 128-row tile

  // ---- S = Q.K^T ----
  f32x4 sacc[2][5];
#pragma unroll
  for (int mf = 0; mf < 2; ++mf)
#pragma unroll
    for (int t = 0; t < 5; ++t) sacc[mf][t] = (f32x4){0.f, 0.f, 0.f, 0.f};

#pragma unroll
  for (int k = 0; k < 2; ++k) {
    bf16x8 aq[2];
#pragma unroll
    for (int mf = 0; mf < 2; ++mf)
      aq[mf] = *(const bf16x8*)(&Qs[(wrow + mf * 16 + lm) * 72 + k * 32 + quad * 8]);
#pragma unroll
    for (int t = 0; t < 5; ++t) {
      const bf16x8 bk = *(const bf16x8*)(&Ks[(t * 16 + lm) * 72 + k * 32 + quad * 8]);
#pragma unroll
      for (int mf = 0; mf < 2; ++mf)
        sacc[mf][t] = __builtin_amdgcn_mfma_f32_16x16x32_bf16(aq[mf], bk, sacc[mf][t], 0, 0, 0);
    }
  }

  // ---- softmax (rows = quad*4+r within each 16-row m-frag) ----
  const float scale = 0.15811388300841897f;   // 1/sqrt(40)
  float sv[2][5][4];
  float rl[2][4];
#pragma unroll
  for (int mf = 0; mf < 2; ++mf) {
#pragma unroll
    for (int t = 0; t < 5; ++t)
#pragma unroll
      for (int r = 0; r < 4; ++r) {
        float v = sacc[mf][t][r] * scale;
        if (t == 4 && lm >= 13) v = -1e30f;   // mask keys 77..79
        sv[mf][t][r] = v;
      }
#pragma unroll
    for (int r = 0; r < 4; ++r) {
      float m = sv[mf][0][r];
#pragma unroll
      for (int t = 1; t < 5; ++t) m = fmaxf(m, sv[mf][t][r]);
#pragma unroll
      for (int d = 1; d < 16; d <<= 1) m = fmaxf(m, __shfl_xor(m, d));
      float l = 0.f;
#pragma unroll
      for (int t = 0; t < 5; ++t) {
        const float e = __expf(sv[mf][t][r] - m);
        sv[mf][t][r] = e;
        l += e;
      }
#pragma unroll
      for (int d = 1; d < 16; d <<= 1) l += __shfl_xor(l, d);
      rl[mf][r] = 1.f / l;
    }
  }

  __syncthreads();   // all S-phase reads of Qs/Ks done before Ps overlay

  // ---- P -> LDS (A-layout source), zero cols 80..95 (keys pad for PV) ----
  unsigned short* Pw = Ps + wave * 32 * 104;
#pragma unroll
  for (int mf = 0; mf < 2; ++mf)
#pragma unroll
    for (int t = 0; t < 5; ++t)
#pragma unroll
      for (int r = 0; r < 4; ++r)
        Pw[(mf * 16 + quad * 4 + r) * 104 + t * 16 + lm] = f2bf(sv[mf][t][r]);
  {
    const int row = lane >> 1, half = lane & 1;
    *(uint4*)(&Pw[row * 104 + 80 + half * 8]) = (uint4){0u, 0u, 0u, 0u};
  }
  __syncthreads();

  // ---- O = P.V  (K = 96 keys, N = 48 dims) ----
  f32x4 oacc[2][3];
#pragma unroll
  for (int mf = 0; mf < 2; ++mf)
#pragma unroll
    for (int n = 0; n < 3; ++n) oacc[mf][n] = (f32x4){0.f, 0.f, 0.f, 0.f};

#pragma unroll
  for (int k = 0; k < 3; ++k) {
    bf16x8 ap[2];
#pragma unroll
    for (int mf = 0; mf < 2; ++mf)
      ap[mf] = *(const bf16x8*)(&Pw[(mf * 16 + lm) * 104 + k * 32 + quad * 8]);
#pragma unroll
    for (int n = 0; n < 3; ++n) {
      const bf16x8 bv = *(const bf16x8*)(&Vt[(n * 16 + lm) * 104 + k * 32 + quad * 8]);
#pragma unroll
      for (int mf = 0; mf < 2; ++mf)
        oacc[mf][n] = __builtin_amdgcn_mfma_f32_16x16x32_bf16(ap[mf], bv, oacc[mf][n], 0, 0, 0);
    }
  }

  // ---- store O (bf16) over the Q slice ----
#pragma unroll
  for (int mf = 0; mf < 2; ++mf)
#pragma unroll
    for (int n = 0; n < 3; ++n) {
      const int col = n * 16 + lm;
      if (col < DH_) {
#pragma unroll
        for (int r = 0; r < 4; ++r) {
          const int row = wrow + mf * 16 + quad * 4 + r;
          QO[qbase + (size_t)row * IN_ + col] = f2bf(oacc[mf][n][r] * rl[mf][r]);
        }
      }
    }
}

// ---------------------------------------------------------------------------
extern "C" void kernel_launch(void* const* d_in, const int* in_sizes, int n_in,
                              void* d_out, int out_size, void* d_ws,
                              size_t ws_size, hipStream_t stream)
{
  const float* x   = (const float*)d_in[0];
  const float* ctx = (const float*)d_in[1];
  const float* Wq  = (const float*)d_in[2];
  const float* Wk  = (const float*)d_in[3];
  const float* Wv  = (const float*)d_in[4];
  const float* Wo  = (const float*)d_in[5];
  const float* bo  = (const float*)d_in[6];
  const float* gq  = (const float*)d_in[7];
  const float* gk  = (const float*)d_in[8];
  const float* gv  = (const float*)d_in[9];
  const float* go  = (const float*)d_in[10];
  float* out = (float*)d_out;

  // Workspace carve-up (89,276,416 B total; harness gives >= 90 MB):
  //   q_ws: [131072, 320] bf16  (Q, overwritten in-place with O)
  //   Khb : [32, 8, 80, 64] bf16 (zero-padded K)
  //   Vtb : [32, 8, 48, 96] bf16 (zero-padded V^T)
  //   Wqb, Wob: [320, 320] bf16
  char* ws = (char*)d_ws;
  unsigned short* q_ws = (unsigned short*)ws;
  size_t off = (size_t)M_ * IN_ * 2;
  unsigned short* Khb = (unsigned short*)(ws + off); off += (size_t)B_ * H_ * NKP_ * KQ_ * 2;
  unsigned short* Vtb = (unsigned short*)(ws + off); off += (size_t)B_ * H_ * DHP_ * NKP2_ * 2;
  unsigned short* Wqb = (unsigned short*)(ws + off); off += (size_t)IN_ * IN_ * 2;
  unsigned short* Wob = (unsigned short*)(ws + off);

  hipMemsetAsync(Khb, 0, (size_t)B_ * H_ * NKP_ * KQ_ * 2, stream);
  hipMemsetAsync(Vtb, 0, (size_t)B_ * H_ * DHP_ * NKP2_ * 2, stream);

  wcvt<<<dim3(IN_ * IN_ / 4 / 256, 2), dim3(256), 0, stream>>>(Wq, Wo, Wqb, Wob);
  kv_proj<<<dim3(B_ * NK_ / 8), dim3(320), 0, stream>>>(ctx, Wk, Wv, gk, gv, Khb, Vtb);
  gemm_proj<0><<<dim3(M_ / 64, IN_ / 64), dim3(256), 0, stream>>>(
      x, Wqb, gq, nullptr, q_ws);
  attn_mfma<<<dim3(NQ_ / QT_, H_, B_), dim3(256), 0, stream>>>(Khb, Vtb, q_ws);
  gemm_proj<1><<<dim3(M_ / 64, IN_ / 64), dim3(256), 0, stream>>>(
      q_ws, Wob, go, bo, out);
}